// Round 3
// baseline (1335.116 us; speedup 1.0000x reference)
//
#include <hip/hip_runtime.h>

#define NN 50000
#define EE 400000
#define FF 128
#define NRBF 20
#define MAXDEG 64
#define NT 16
#define KT 32
#define PI_OVER_CUT 0.6283185307179586f   // pi / 5.0

// Swizzled weight-tile accessor: tile is 128 rows x 32 cols, row stride 32,
// element (g,k) stored at [g*32 + ((k+g)&31)]. Read by lane g0 at fixed k:
// bank = (k+g0)%32 -> 2-way across 64 lanes = free. No padding needed.
#define WREAD(wb, g, k) wb[((g) << 5) + (((k) + (g)) & 31)]

// Stage 128 rows x 32 cols of W (row length ldw) starting at col j0.
// 256 threads x 4 float4. Global: 8 threads/row -> row-contiguous (2 lines/row).
// LDS writes <=2-way conflicted under the swizzle.
__device__ __forceinline__ void stage_w(const float* __restrict__ W, int ldw,
                                        int j0, float* __restrict__ wb, int t) {
    #pragma unroll
    for (int p = 0; p < 4; ++p) {
        int r = t + 256 * p;          // 0..1023
        int g = r >> 3;               // 0..127
        int c4 = (r & 7) * 4;         // 0,4,...,28
        float4 w = *(const float4*)&W[(size_t)g * ldw + j0 + c4];
        int base = g << 5;
        wb[base + ((c4 + 0 + g) & 31)] = w.x;
        wb[base + ((c4 + 1 + g) & 31)] = w.y;
        wb[base + ((c4 + 2 + g) & 31)] = w.z;
        wb[base + ((c4 + 3 + g) & 31)] = w.w;
    }
}

// ---------------------------------------------------------------------------
__global__ __launch_bounds__(256) void k_zero(int* __restrict__ counts) {
    int i = blockIdx.x * 256 + threadIdx.x;
    if (i < NN) counts[i] = 0;
}

__global__ __launch_bounds__(256) void k_bucket(const int* __restrict__ dst,
                                                int* __restrict__ counts,
                                                int* __restrict__ slots) {
    int e = blockIdx.x * 256 + threadIdx.x;
    if (e < EE) {
        int n = dst[e];
        int slot = atomicAdd(&counts[n], 1);
        if (slot < MAXDEG) slots[n * MAXDEG + slot] = e;
    }
}

// ---------------------------------------------------------------------------
// K1: s0 = emb[z]; phi_s (Wp2 rows 0:128), phi_v (rows 256:384).
// LDS 32 KB -> 4+ blocks/CU.
__global__ __launch_bounds__(256) void k_node_phi(
    const float* __restrict__ emb, const int* __restrict__ z,
    const float* __restrict__ Wp1, const float* __restrict__ bp1,
    const float* __restrict__ Wp2, const float* __restrict__ bp2,
    float* __restrict__ phi_s, float* __restrict__ phi_v,
    float* __restrict__ s_io)
{
    __shared__ float s_t[NT][FF];    // 8 KB
    __shared__ float h1_t[NT][FF];   // 8 KB
    __shared__ float wb[128 * 32];   // 16 KB
    const int t  = threadIdx.x;
    const int g0 = t & 63;
    const int h  = t >> 6;
    const int n0 = blockIdx.x * NT;

    for (int i = t; i < NT * FF; i += 256) {
        int n = i >> 7, f = i & 127;
        s_t[n][f] = emb[(size_t)z[n0 + n] * FF + f];
    }

    // ---- phase 1: h1 = silu(Wp1 @ s + bp1) ----
    float acc[2][4];
    #pragma unroll
    for (int a = 0; a < 2; a++)
        #pragma unroll
        for (int i = 0; i < 4; i++) acc[a][i] = 0.f;

    for (int jt = 0; jt < 4; ++jt) {
        const int j0 = jt * KT;
        __syncthreads();
        stage_w(Wp1, FF, j0, wb, t);
        __syncthreads();
        for (int kk = 0; kk < KT; kk += 4) {
            float wa[4], wc[4];
            #pragma unroll
            for (int q = 0; q < 4; ++q) {
                wa[q] = WREAD(wb, g0, kk + q);
                wc[q] = WREAD(wb, g0 + 64, kk + q);
            }
            #pragma unroll
            for (int i = 0; i < 4; ++i) {
                int n = h + 4 * i;
                float4 x4 = *(const float4*)&s_t[n][j0 + kk];
                acc[0][i] += wa[0]*x4.x + wa[1]*x4.y + wa[2]*x4.z + wa[3]*x4.w;
                acc[1][i] += wc[0]*x4.x + wc[1]*x4.y + wc[2]*x4.z + wc[3]*x4.w;
            }
        }
    }
    __syncthreads();
    {
        float b1a = bp1[g0], b1b = bp1[g0 + 64];
        #pragma unroll
        for (int i = 0; i < 4; i++) {
            int n = h + 4 * i;
            float xa = acc[0][i] + b1a;
            float xb = acc[1][i] + b1b;
            h1_t[n][g0]      = xa / (1.f + __expf(-xa));
            h1_t[n][g0 + 64] = xb / (1.f + __expf(-xb));
        }
    }

    // ---- phase 2: phi_s / phi_v ----
    float A[2][2][4];   // [grp][half][i]
    #pragma unroll
    for (int gR = 0; gR < 2; gR++)
        #pragma unroll
        for (int a = 0; a < 2; a++)
            #pragma unroll
            for (int i = 0; i < 4; i++) A[gR][a][i] = 0.f;

    #pragma unroll
    for (int gR = 0; gR < 2; ++gR) {
        const float* Wsrc = Wp2 + (size_t)(gR == 0 ? 0 : 256) * FF;
        for (int jt = 0; jt < 4; ++jt) {
            const int j0 = jt * KT;
            __syncthreads();
            stage_w(Wsrc, FF, j0, wb, t);
            __syncthreads();
            for (int kk = 0; kk < KT; kk += 4) {
                float wa[4], wc[4];
                #pragma unroll
                for (int q = 0; q < 4; ++q) {
                    wa[q] = WREAD(wb, g0, kk + q);
                    wc[q] = WREAD(wb, g0 + 64, kk + q);
                }
                #pragma unroll
                for (int i = 0; i < 4; ++i) {
                    int n = h + 4 * i;
                    float4 x4 = *(const float4*)&h1_t[n][j0 + kk];
                    A[gR][0][i] += wa[0]*x4.x + wa[1]*x4.y + wa[2]*x4.z + wa[3]*x4.w;
                    A[gR][1][i] += wc[0]*x4.x + wc[1]*x4.y + wc[2]*x4.z + wc[3]*x4.w;
                }
            }
        }
    }
    {
        float bsa = bp2[g0], bsb = bp2[g0 + 64];
        float bva = bp2[256 + g0], bvb = bp2[256 + g0 + 64];
        #pragma unroll
        for (int i = 0; i < 4; i++) {
            int n = h + 4 * i;
            size_t gi = (size_t)(n0 + n) * FF;
            phi_s[gi + g0]      = A[0][0][i] + bsa;
            phi_s[gi + g0 + 64] = A[0][1][i] + bsb;
            phi_v[gi + g0]      = A[1][0][i] + bva;
            phi_v[gi + g0 + 64] = A[1][1][i] + bvb;
            s_io[gi + g0]       = s_t[n][g0];
            s_io[gi + g0 + 64]  = s_t[n][g0 + 64];
        }
    }
}

// ---------------------------------------------------------------------------
// K2: per-destination-node message accumulation (unchanged).
__global__ __launch_bounds__(128) void k_edge(
    const float* __restrict__ pos,
    const float* __restrict__ Ww, const float* __restrict__ bw,
    const int* __restrict__ src,
    const int* __restrict__ counts, const int* __restrict__ slots,
    const float* __restrict__ phi_s, const float* __restrict__ phi_v,
    float* __restrict__ s_io, float* __restrict__ v_io)
{
    const int n = blockIdx.x;
    const int f = threadIdx.x;
    const int lane = threadIdx.x & 63;

    float ww_s[NRBF], ww_v[NRBF];
    #pragma unroll
    for (int k = 0; k < NRBF; k++) {
        ww_s[k] = Ww[f * NRBF + k];
        ww_v[k] = Ww[(256 + f) * NRBF + k];
    }
    const float bws = bw[f], bwv = bw[256 + f];
    const float px = pos[3 * n], py = pos[3 * n + 1], pz = pos[3 * n + 2];

    float acc_s = 0.f, av0 = 0.f, av1 = 0.f, av2 = 0.f;
    int deg = counts[n];
    deg = deg > MAXDEG ? MAXDEG : deg;

    for (int i = 0; i < deg; i++) {
        int e  = slots[n * MAXDEG + i];
        int sI = src[e];
        float rx = px - pos[3 * sI];
        float ry = py - pos[3 * sI + 1];
        float rz = pz - pos[3 * sI + 2];
        float d = sqrtf(rx * rx + ry * ry + rz * rz);
        d = fmaxf(d, 1e-9f);
        float dinv = 1.f / d;
        int kk = lane < NRBF ? lane : (NRBF - 1);
        float rbf_l = __sinf((float)(kk + 1) * PI_OVER_CUT * d) * dinv;
        int rbf_i = __float_as_int(rbf_l);
        float wfs = bws, wfv = bwv;
        #pragma unroll
        for (int k = 0; k < NRBF; k++) {
            float rk = __int_as_float(__builtin_amdgcn_readlane(rbf_i, k));
            wfs = fmaf(ww_s[k], rk, wfs);
            wfv = fmaf(ww_v[k], rk, wfv);
        }
        float sp_s = phi_s[(size_t)sI * FF + f] * wfs;
        float sp_v = phi_v[(size_t)sI * FF + f] * wfv;
        acc_s += sp_s;
        av0 = fmaf(sp_v, rx * dinv, av0);
        av1 = fmaf(sp_v, ry * dinv, av1);
        av2 = fmaf(sp_v, rz * dinv, av2);
    }
    size_t gi = (size_t)n * FF + f;
    s_io[gi] += acc_s;
    v_io[gi * 3 + 0] = av0;
    v_io[gi * 3 + 1] = av1;
    v_io[gi * 3 + 2] = av2;
}

// ---------------------------------------------------------------------------
// K3: fused update block. LDS exactly 64 KB -> 2 blocks/CU.
// xn_t holds Vn during phase 2, then is overwritten with h1 for phase 3.
__global__ __launch_bounds__(256) void k_update(
    const float* __restrict__ Wu, const float* __restrict__ bu,
    const float* __restrict__ Wv, const float* __restrict__ bv,
    const float* __restrict__ Wu1, const float* __restrict__ bu1,
    const float* __restrict__ Wu2, const float* __restrict__ bu2,
    float* __restrict__ s_io, float* __restrict__ v_io)
{
    __shared__ float v_t[NT][FF][4];   // 32 KB (float4-padded for b128 broadcast)
    __shared__ float s_t[NT][FF];      // 8 KB
    __shared__ float xn_t[NT][FF];     // 8 KB (Vn, then h1)
    __shared__ float wb[128 * 32];     // 16 KB swizzled weight tile
    const int t  = threadIdx.x;
    const int g0 = t & 63;
    const int h  = t >> 6;
    const int n0 = blockIdx.x * NT;

    for (int i = t; i < NT * FF; i += 256) {
        int n = i >> 7, f = i & 127;
        size_t gi = (size_t)(n0 + n) * FF + f;
        s_t[n][f]    = s_io[gi];
        v_t[n][f][0] = v_io[gi * 3 + 0];
        v_t[n][f][1] = v_io[gi * 3 + 1];
        v_t[n][f][2] = v_io[gi * 3 + 2];
        v_t[n][f][3] = 0.f;
    }

    // ---- phase 1: U = v@Wu^T, V = v@Wv^T (per-component) ----
    float U[2][4][3], V[2][4][3];
    #pragma unroll
    for (int a = 0; a < 2; a++)
        #pragma unroll
        for (int i = 0; i < 4; i++)
            #pragma unroll
            for (int c = 0; c < 3; c++) { U[a][i][c] = 0.f; V[a][i][c] = 0.f; }

    for (int jt = 0; jt < 4; ++jt) {
        const int j0 = jt * KT;
        // Wu tile
        __syncthreads();
        stage_w(Wu, FF, j0, wb, t);
        __syncthreads();
        for (int k = 0; k < KT; ++k) {
            float wua = WREAD(wb, g0, k);
            float wub = WREAD(wb, g0 + 64, k);
            #pragma unroll
            for (int i = 0; i < 4; ++i) {
                float4 vv = *(const float4*)&v_t[h + 4 * i][j0 + k][0];
                U[0][i][0] = fmaf(wua, vv.x, U[0][i][0]);
                U[0][i][1] = fmaf(wua, vv.y, U[0][i][1]);
                U[0][i][2] = fmaf(wua, vv.z, U[0][i][2]);
                U[1][i][0] = fmaf(wub, vv.x, U[1][i][0]);
                U[1][i][1] = fmaf(wub, vv.y, U[1][i][1]);
                U[1][i][2] = fmaf(wub, vv.z, U[1][i][2]);
            }
        }
        // Wv tile
        __syncthreads();
        stage_w(Wv, FF, j0, wb, t);
        __syncthreads();
        for (int k = 0; k < KT; ++k) {
            float wva = WREAD(wb, g0, k);
            float wvb = WREAD(wb, g0 + 64, k);
            #pragma unroll
            for (int i = 0; i < 4; ++i) {
                float4 vv = *(const float4*)&v_t[h + 4 * i][j0 + k][0];
                V[0][i][0] = fmaf(wva, vv.x, V[0][i][0]);
                V[0][i][1] = fmaf(wva, vv.y, V[0][i][1]);
                V[0][i][2] = fmaf(wva, vv.z, V[0][i][2]);
                V[1][i][0] = fmaf(wvb, vv.x, V[1][i][0]);
                V[1][i][1] = fmaf(wvb, vv.y, V[1][i][1]);
                V[1][i][2] = fmaf(wvb, vv.z, V[1][i][2]);
            }
        }
    }

    float uv[2][4];
    {
        float buv[2] = { bu[g0], bu[g0 + 64] };
        float bvv[2] = { bv[g0], bv[g0 + 64] };
        #pragma unroll
        for (int a = 0; a < 2; a++) {
            #pragma unroll
            for (int i = 0; i < 4; i++) {
                const int n = h + 4 * i;
                #pragma unroll
                for (int c = 0; c < 3; c++) {
                    U[a][i][c] += buv[a];
                    V[a][i][c] += bvv[a];
                }
                float vx = V[a][i][0], vy = V[a][i][1], vz = V[a][i][2];
                xn_t[n][g0 + 64 * a] = sqrtf(vx * vx + vy * vy + vz * vz);
                uv[a][i] = U[a][i][0] * vx + U[a][i][1] * vy + U[a][i][2] * vz;
            }
        }
    }
    // xn_t (Vn) writes ordered before phase-2 reads by the next pre-stage barrier

    // ---- phase 2: h1 = silu(Wu1 @ [s;Vn] + bu1), K=256 ----
    float hacc[2][4];
    #pragma unroll
    for (int a = 0; a < 2; a++)
        #pragma unroll
        for (int i = 0; i < 4; i++) hacc[a][i] = 0.f;

    for (int jt = 0; jt < 8; ++jt) {
        const int j0 = jt * KT;
        __syncthreads();
        stage_w(Wu1, 256, j0, wb, t);
        __syncthreads();
        const float* xs = (jt < 4) ? &s_t[0][0] : &xn_t[0][0];
        const int jl = (jt & 3) * KT;
        for (int kk = 0; kk < KT; kk += 4) {
            float wa[4], wc[4];
            #pragma unroll
            for (int q = 0; q < 4; ++q) {
                wa[q] = WREAD(wb, g0, kk + q);
                wc[q] = WREAD(wb, g0 + 64, kk + q);
            }
            #pragma unroll
            for (int i = 0; i < 4; ++i) {
                int n = h + 4 * i;
                float4 x4 = *(const float4*)&xs[n * FF + jl + kk];
                hacc[0][i] += wa[0]*x4.x + wa[1]*x4.y + wa[2]*x4.z + wa[3]*x4.w;
                hacc[1][i] += wc[0]*x4.x + wc[1]*x4.y + wc[2]*x4.z + wc[3]*x4.w;
            }
        }
    }
    __syncthreads();   // all reads of Vn from xn_t complete
    {
        float b1a = bu1[g0], b1b = bu1[g0 + 64];
        #pragma unroll
        for (int i = 0; i < 4; i++) {
            int n = h + 4 * i;
            float xa = hacc[0][i] + b1a;
            float xb = hacc[1][i] + b1b;
            xn_t[n][g0]      = xa / (1.f + __expf(-xa));   // h1 overwrites Vn
            xn_t[n][g0 + 64] = xb / (1.f + __expf(-xb));
        }
    }
    // h1 writes ordered before phase-3 reads by the next pre-stage barrier

    // ---- phase 3: a = Wu2 @ h1 (3 row groups of 128) ----
    float A[3][2][4];
    #pragma unroll
    for (int r = 0; r < 3; r++)
        #pragma unroll
        for (int a = 0; a < 2; a++)
            #pragma unroll
            for (int i = 0; i < 4; i++) A[r][a][i] = 0.f;

    #pragma unroll
    for (int rg = 0; rg < 3; ++rg) {
        const float* Wsrc = Wu2 + (size_t)rg * 128 * FF;
        for (int jt = 0; jt < 4; ++jt) {
            const int j0 = jt * KT;
            __syncthreads();
            stage_w(Wsrc, FF, j0, wb, t);
            __syncthreads();
            for (int kk = 0; kk < KT; kk += 4) {
                float wa[4], wc[4];
                #pragma unroll
                for (int q = 0; q < 4; ++q) {
                    wa[q] = WREAD(wb, g0, kk + q);
                    wc[q] = WREAD(wb, g0 + 64, kk + q);
                }
                #pragma unroll
                for (int i = 0; i < 4; ++i) {
                    int n = h + 4 * i;
                    float4 x4 = *(const float4*)&xn_t[n][j0 + kk];
                    A[rg][0][i] += wa[0]*x4.x + wa[1]*x4.y + wa[2]*x4.z + wa[3]*x4.w;
                    A[rg][1][i] += wc[0]*x4.x + wc[1]*x4.y + wc[2]*x4.z + wc[3]*x4.w;
                }
            }
        }
    }

    {
        float ba1[2] = { bu2[g0],       bu2[g0 + 64]  };
        float ba2[2] = { bu2[128 + g0], bu2[192 + g0] };
        float ba3[2] = { bu2[256 + g0], bu2[320 + g0] };
        #pragma unroll
        for (int a = 0; a < 2; a++) {
            const int g = g0 + 64 * a;
            #pragma unroll
            for (int i = 0; i < 4; i++) {
                const int n = h + 4 * i;
                const size_t gi = (size_t)(n0 + n) * FF + g;
                float aa1 = A[0][a][i] + ba1[a];
                float aa2 = A[1][a][i] + ba2[a];
                float aa3 = A[2][a][i] + ba3[a];
                s_io[gi] = s_t[n][g] + aa2 + uv[a][i] * aa3;
                v_io[gi * 3 + 0] = v_t[n][g][0] + U[a][i][0] * aa1;
                v_io[gi * 3 + 1] = v_t[n][g][1] + U[a][i][1] * aa1;
                v_io[gi * 3 + 2] = v_t[n][g][2] + U[a][i][2] * aa1;
            }
        }
    }
}

// ---------------------------------------------------------------------------
extern "C" void kernel_launch(void* const* d_in, const int* in_sizes, int n_in,
                              void* d_out, int out_size, void* d_ws, size_t ws_size,
                              hipStream_t stream)
{
    const float* pos = (const float*)d_in[0];
    const float* emb = (const float*)d_in[1];
    const float* Wp1 = (const float*)d_in[2];
    const float* bp1 = (const float*)d_in[3];
    const float* Wp2 = (const float*)d_in[4];
    const float* bp2 = (const float*)d_in[5];
    const float* Ww  = (const float*)d_in[6];
    const float* bw  = (const float*)d_in[7];
    const float* Wu  = (const float*)d_in[8];
    const float* bu  = (const float*)d_in[9];
    const float* Wv  = (const float*)d_in[10];
    const float* bv  = (const float*)d_in[11];
    const float* Wu1 = (const float*)d_in[12];
    const float* bu1 = (const float*)d_in[13];
    const float* Wu2 = (const float*)d_in[14];
    const float* bu2 = (const float*)d_in[15];
    const int* z   = (const int*)d_in[16];
    const int* src = (const int*)d_in[17];
    const int* dst = (const int*)d_in[18];

    float* s_io = (float*)d_out;
    float* v_io = (float*)d_out + (size_t)NN * FF;

    char* ws = (char*)d_ws;
    float* phi_s = (float*)ws;
    float* phi_v = phi_s + (size_t)NN * FF;
    int*   counts = (int*)(phi_v + (size_t)NN * FF);
    int*   slots  = counts + NN;

    k_zero  <<<(NN + 255) / 256, 256, 0, stream>>>(counts);
    k_bucket<<<(EE + 255) / 256, 256, 0, stream>>>(dst, counts, slots);
    k_node_phi<<<NN / NT, 256, 0, stream>>>(emb, z, Wp1, bp1, Wp2, bp2,
                                            phi_s, phi_v, s_io);
    k_edge<<<NN, 128, 0, stream>>>(pos, Ww, bw, src, counts, slots,
                                   phi_s, phi_v, s_io, v_io);
    k_update<<<NN / NT, 256, 0, stream>>>(Wu, bu, Wv, bv, Wu1, bu1, Wu2, bu2,
                                          s_io, v_io);
}